// Round 10
// baseline (174.208 us; speedup 1.0000x reference)
//
#include <hip/hip_runtime.h>

#define NB 128
#define NM 1024
#define NK 32
#define NS 12                   // per-quarter survivor slots (avg ~7.6; P(>12)~3%)
#define CUT2 25.0f
#define CUT2_BITS 0x41C80000u   // bit pattern of 25.0f
#define KEYMASK   0xFFFFFC00u   // top 22 bits d2, low 10 bits index
#define INV_CELL  (1.0f/5.2f)   // 5x5x5 cells of 5.2 >= cutoff
#define NCELL3    125
#define SSTRIDE   1032          // sortedg row stride: 1024 atoms + 8 sentinels

// workspace layout (bytes)
#define OFF_ORIG   ((size_t)NB * SSTRIDE * 16)            // sortedg 2.11 MB
#define OFF_STARTS (OFF_ORIG + (size_t)(256u << 10))      // origid  256 KB
#define OFF_INV    (OFF_STARTS + (size_t)(32u << 10))     // startsg  32 KB
#define OFF_KEYS   (OFF_INV + (size_t)(256u << 10))       // invpos  256 KB
#define WS_NEEDED  (OFF_KEYS + (size_t)NB * NM * NK * 2)  // keys    8.39 MB

typedef unsigned int   u32;
typedef unsigned short u16;
typedef float vf4 __attribute__((ext_vector_type(4)));

// Prepass: bin atoms into 125 cells per molecule, write cell-sorted scan-form
// coords {-2x,-2y,-2z,|p|^2} + origid + invpos + cell-start table.
// 8 sentinel atoms (coords 1e15 -> d2 ~1e30) close each molecule's row: pad
// candidates (j=1024) fail the cutoff with no per-candidate test.
__global__ __launch_bounds__(256) void pack_bin(const float* __restrict__ pos,
                                                float4* __restrict__ sortedg,
                                                u16* __restrict__ origid,
                                                u16* __restrict__ invpos,
                                                u16* __restrict__ startsg)
{
  __shared__ u32 hist[NCELL3 + 1];
  __shared__ u32 starts[NCELL3 + 1];
  __shared__ u32 cur[NCELL3];
  const int tid = threadIdx.x;
  const int mb  = blockIdx.x;
  if (tid <= NCELL3) hist[tid] = 0;
  __syncthreads();

  float xx[4], yy[4], zz[4];
  int cid[4];
#pragma unroll
  for (int k = 0; k < 4; ++k) {
    int i  = k * 256 + tid;
    int gi = mb * NM + i;
    float x = pos[3*gi+0], y = pos[3*gi+1], z = pos[3*gi+2];
    xx[k] = x; yy[k] = y; zz[k] = z;
    int cx = (int)(x * INV_CELL); cx = cx > 4 ? 4 : cx;
    int cy = (int)(y * INV_CELL); cy = cy > 4 ? 4 : cy;
    int cz = (int)(z * INV_CELL); cz = cz > 4 ? 4 : cz;
    cid[k] = (cz * 5 + cy) * 5 + cx;
    atomicAdd(&hist[cid[k]], 1u);
  }
  __syncthreads();
  if (tid == 0) {
    u32 run = 0;
    for (int i = 0; i < NCELL3; ++i) { starts[i] = run; run += hist[i]; }
    starts[NCELL3] = run;                        // = 1024
  }
  __syncthreads();
  if (tid <= NCELL3) startsg[mb*(NCELL3+1) + tid] = (u16)starts[tid];
  if (tid <  NCELL3) cur[tid] = starts[tid];
  __syncthreads();
#pragma unroll
  for (int k = 0; k < 4; ++k) {
    int i = k * 256 + tid;
    u32 p = atomicAdd(&cur[cid[k]], 1u);
    float x = xx[k], y = yy[k], z = zz[k];
    sortedg[mb*SSTRIDE + p] = make_float4(-2.f*x, -2.f*y, -2.f*z, x*x + y*y + z*z);
    origid[mb*NM + p]  = (u16)i;
    invpos[mb*NM + i]  = (u16)p;
  }
  if (tid < 8)                                    // sentinels
    sortedg[mb*SSTRIDE + 1024 + tid] = make_float4(-2e15f, -2e15f, -2e15f, 1e30f);
}

__device__ __forceinline__ void ce_asc(u32 &a, u32 &b) {
  u32 mn = a < b ? a : b;
  u32 mx = a < b ? b : a;
  a = mn; b = mx;
}

template <int N, int K, int D>
__device__ __forceinline__ void bitonic_pass(u32* r) {
#pragma unroll
  for (int i = 0; i < N; ++i)
    if ((i & D) == 0) {
      if ((i & K) == 0) ce_asc(r[i], r[i | D]);
      else              ce_asc(r[i | D], r[i]);
    }
}

// R15: scan inner loop widened to 4 broadcast loads in flight (slots j, j+4,
// j+8, j+12; past-re slots use sentinel idx 1024 which fails the cutoff into
// the dead slot). Select machinery otherwise identical to R14 (passed).
template <bool SPLIT>
__global__ __launch_bounds__(256, 8) void radius_knn(const float4* __restrict__ sortedg,
                                                     const u16* __restrict__ origg,
                                                     const u16* __restrict__ startsg,
                                                     u16* __restrict__ keys,
                                                     float* __restrict__ out)
{
  __shared__ u32 lmem[4096];    // 16KB: lists (12KB), later publish buf (16KB)
  __shared__ u16 st_s[128];     // 256B cell-start table
  __shared__ u16 orig_s[NM];    // 2KB sorted-pos -> orig (mono instantiation only)
  u32* lists = lmem;            // [NS][256] u32 = 12KB

  const int tid     = threadIdx.x;
  const int ctr     = tid & 63;
  const int quarter = tid >> 6;          // wave index
  const int molb    = blockIdx.x & 127;  // same-XCD blocks share molecule
  const int grp     = blockIdx.x >> 7;
  const int spos    = grp * 64 + ctr;    // center = sorted position
  const int molbase  = molb * NM;        // origg/keys stride
  const int molbaseS = molb * SSTRIDE;   // sortedg stride (with sentinels)

  if constexpr (!SPLIT)
    for (int t = tid; t < NM; t += 256) orig_s[t] = origg[molbase + t];
  if (tid <= NCELL3) st_s[tid] = startsg[molb*(NCELL3+1) + tid];

  const float4 mc  = sortedg[molbaseS + spos];
  const float mex = -0.5f*mc.x, mey = -0.5f*mc.y, mez = -0.5f*mc.z;
  const float mew = mc.w;

  // block cell bounds (every wave reduces over the same 64 centers)
  int cx = (int)(mex * INV_CELL); cx = cx > 4 ? 4 : cx;
  int cy = (int)(mey * INV_CELL); cy = cy > 4 ? 4 : cy;
  int cz = (int)(mez * INV_CELL); cz = cz > 4 ? 4 : cz;
  int mnx = cx, mxx = cx, mny = cy, mxy = cy, mnz = cz, mxz = cz;
#pragma unroll
  for (int m = 32; m; m >>= 1) {
    mnx = min(mnx, __shfl_xor(mnx, m, 64)); mxx = max(mxx, __shfl_xor(mxx, m, 64));
    mny = min(mny, __shfl_xor(mny, m, 64)); mxy = max(mxy, __shfl_xor(mxy, m, 64));
    mnz = min(mnz, __shfl_xor(mnz, m, 64)); mxz = max(mxz, __shfl_xor(mxz, m, 64));
  }
  __syncthreads();                                   // st_s (and orig_s) ready

  const int zlo = max(mnz-1, 0), zhi = min(mxz+1, 4);
  const int ylo = max(mny-1, 0), yhi = min(mxy+1, 4);
  const int xlo = max(mnx-1, 0), xhi = min(mxx+1, 4);

  // ---- phase 1: scan dilated-bbox rows, quarter-interleaved mod 4,
  //      4 broadcast loads in flight ----
  int cnt = 0;
#define PROC(cj, jv)                                                        \
    {                                                                       \
      float d2 = fmaxf(__builtin_fmaf(mex, cj.x, __builtin_fmaf(mey, cj.y, \
                 __builtin_fmaf(mez, cj.z, mew + cj.w))), 0.f);             \
      u32 key = (__float_as_uint(d2) & KEYMASK) | (u32)((jv) & 1023);       \
      int slot = cnt < NS ? cnt : (NS - 1);                                 \
      lists[slot * 256 + tid] = key;                                        \
      cnt += (d2 <= CUT2) ? 1 : 0;                                          \
    }
  for (int rz = zlo; rz <= zhi; ++rz)
    for (int ry = ylo; ry <= yhi; ++ry) {
      const int rowb = (rz*5 + ry)*5;
      const int rs = st_s[rowb + xlo];
      const int re = st_s[rowb + xhi + 1];
      for (int j0 = rs + quarter; j0 < re; j0 += 16) {
        const int ja = j0;
        const int jb = j0 + 4  < re ? j0 + 4  : 1024;   // sentinel: fails cutoff
        const int jc = j0 + 8  < re ? j0 + 8  : 1024;
        const int jd = j0 + 12 < re ? j0 + 12 : 1024;
        float4 ca = sortedg[molbaseS + ja];
        float4 cb = sortedg[molbaseS + jb];
        float4 cc = sortedg[molbaseS + jc];
        float4 cd = sortedg[molbaseS + jd];
        PROC(ca, ja)
        PROC(cb, jb)
        PROC(cc, jc)
        PROC(cd, jd)
      }
    }
#undef PROC
  if (cnt > NS) cnt = NS;

  // ---- phase 2: keys straight from LDS + bitonic sort 16 ----
  const u32 PADK = 0x7F800000u | (u32)spos;   // +inf self-pad, sorts last
  u32 r[32];
#pragma unroll
  for (int k = 0; k < 16; ++k)
    r[k] = (k < cnt) ? lists[k * 256 + tid] : PADK;
  bitonic_pass<16, 2, 1>(r);
  bitonic_pass<16, 4, 2>(r); bitonic_pass<16, 4, 1>(r);
  bitonic_pass<16, 8, 4>(r); bitonic_pass<16, 8, 2>(r); bitonic_pass<16, 8, 1>(r);
  bitonic_pass<16,16, 8>(r); bitonic_pass<16,16, 4>(r); bitonic_pass<16,16, 2>(r); bitonic_pass<16,16, 1>(r);

  // ---- phase 3a: symmetric pair merge (q0<->q1, q2<->q3), 16 keys ----
  __syncthreads();                       // lists dead; lmem = publish buf
  {
    u32* myp = lmem + quarter * 1024 + ctr * 16;
#pragma unroll
    for (int k = 0; k < 16; ++k) myp[(k + ctr) & 15] = r[k];   // bank-swizzled
  }
  __syncthreads();
  if (!SPLIT || (quarter & 1) == 0) {    // SPLIT: only publishers need pair-32
    u32* op = lmem + (quarter ^ 1) * 1024 + ctr * 16;
#pragma unroll
    for (int i = 0; i < 16; ++i) r[16 + i] = op[((15 - i) + ctr) & 15]; // desc
    bitonic_pass<32,32,16>(r); bitonic_pass<32,32, 8>(r); bitonic_pass<32,32, 4>(r);
    bitonic_pass<32,32, 2>(r); bitonic_pass<32,32, 1>(r);
  }

  // ---- phase 3b: cross-pair merge ----
  __syncthreads();
  const int pairId = quarter >> 1;
  if ((quarter & 1) == 0) {
    u32* pp = lmem + pairId * 2048 + ctr * 32;
#pragma unroll
    for (int k = 0; k < 32; ++k) pp[(k + ctr) & 31] = r[k];
  }
  __syncthreads();
  if (!SPLIT || quarter == 0) {          // SPLIT: only q0 needs the final 32
    u32* opp = lmem + (1 - pairId) * 2048 + ctr * 32;
#pragma unroll
    for (int t = 0; t < 32; ++t) {
      u32 v = opp[((31 - t) + ctr) & 31];            // other pair, descending
      r[t] = r[t] < v ? r[t] : v;                    // lower half of bitonic-64
    }
    bitonic_pass<32,32,16>(r); bitonic_pass<32,32, 8>(r); bitonic_pass<32,32, 4>(r);
    bitonic_pass<32,32, 2>(r); bitonic_pass<32,32, 1>(r);
  }

  if constexpr (SPLIT) {
    // ---- phase 4 (split): q0 stores packed u16 keys, coalesced by spos ----
    if (quarter == 0) {
      u32 pk[16];
#pragma unroll
      for (int i = 0; i < 16; ++i) {
        u32 klo = r[2*i], khi = r[2*i+1];
        u32 plo = (((klo & KEYMASK) <= CUT2_BITS) ? 1024u : 0u) | (klo & 1023u);
        u32 phi = (((khi & KEYMASK) <= CUT2_BITS) ? 1024u : 0u) | (khi & 1023u);
        pk[i] = plo | (phi << 16);
      }
      uint4* kp = (uint4*)(keys + (size_t)(molbase + spos) * 32);
#pragma unroll
      for (int i = 0; i < 4; ++i)
        kp[i] = make_uint4(pk[4*i], pk[4*i+1], pk[4*i+2], pk[4*i+3]);
    }
    return;
  } else {
    // ---- phase 4 (mono fallback): scattered emit, one role per wave ----
    const int mloc = orig_s[spos];
    const int c = molbase + mloc;
    const long long E = (long long)NB * NM * NK;
    const float base = (float)molbase;
    const float nmex = -mex, nmey = -mey, nmez = -mez;

    if (quarter == 0) {                    // src + dst
      vf4* ps = (vf4*)(out       + (size_t)c * NK);
      vf4* pd = (vf4*)(out +   E + (size_t)c * NK);
      const float fc = (float)c;
      const vf4 dstv = {fc, fc, fc, fc};
#pragma unroll
      for (int q = 0; q < 8; ++q) {
        float sv[4];
#pragma unroll
        for (int u = 0; u < 4; ++u) {
          int idx = (int)(r[4*q + u] & 1023u);
          sv[u] = base + (float)orig_s[idx];
        }
        ps[q] = (vf4){sv[0], sv[1], sv[2], sv[3]};
        pd[q] = dstv;
      }
    } else if (quarter == 1) {             // weights
      vf4* pw = (vf4*)(out + 2*E + (size_t)c * NK);
#pragma unroll
      for (int q = 0; q < 8; ++q) {
        float wv[4];
#pragma unroll
        for (int u = 0; u < 4; ++u) {
          u32 key = r[4*q + u];
          int idx = (int)(key & 1023u);
          float4 cj = sortedg[molbaseS + idx];
          bool valid = (key & KEYMASK) <= CUT2_BITS;
          float vx = __builtin_fmaf(-0.5f, cj.x, nmex);
          float vy = __builtin_fmaf(-0.5f, cj.y, nmey);
          float vz = __builtin_fmaf(-0.5f, cj.z, nmez);
          bool wm  = valid && (idx != spos);
          float d2s = vx*vx + vy*vy + vz*vz;
          wv[u] = wm ? sqrtf(d2s) : 0.0f;
        }
        pw[q] = (vf4){wv[0], wv[1], wv[2], wv[3]};
      }
    } else if (quarter == 2) {             // edge vectors 0..15
      vf4* pv = (vf4*)(out + 3*E + (size_t)c * NK * 3);
#pragma unroll
      for (int q = 0; q < 4; ++q) {
        float vv[12];
#pragma unroll
        for (int u = 0; u < 4; ++u) {
          int idx = (int)(r[4*q + u] & 1023u);
          float4 cj = sortedg[molbaseS + idx];
          vv[3*u+0] = __builtin_fmaf(-0.5f, cj.x, nmex);
          vv[3*u+1] = __builtin_fmaf(-0.5f, cj.y, nmey);
          vv[3*u+2] = __builtin_fmaf(-0.5f, cj.z, nmez);
        }
        pv[3*q+0] = (vf4){vv[0], vv[1], vv[2],  vv[3]};
        pv[3*q+1] = (vf4){vv[4], vv[5], vv[6],  vv[7]};
        pv[3*q+2] = (vf4){vv[8], vv[9], vv[10], vv[11]};
      }
    } else {                               // edge vectors 16..31
      vf4* pv = (vf4*)(out + 3*E + (size_t)c * NK * 3) + 12;
#pragma unroll
      for (int q = 0; q < 4; ++q) {
        float vv[12];
#pragma unroll
        for (int u = 0; u < 4; ++u) {
          int idx = (int)(r[16 + 4*q + u] & 1023u);
          float4 cj = sortedg[molbaseS + idx];
          vv[3*u+0] = __builtin_fmaf(-0.5f, cj.x, nmex);
          vv[3*u+1] = __builtin_fmaf(-0.5f, cj.y, nmey);
          vv[3*u+2] = __builtin_fmaf(-0.5f, cj.z, nmez);
        }
        pv[3*q+0] = (vf4){vv[0], vv[1], vv[2],  vv[3]};
        pv[3*q+1] = (vf4){vv[4], vv[5], vv[6],  vv[7]};
        pv[3*q+2] = (vf4){vv[8], vv[9], vv[10], vv[11]};
      }
    }
  }
}

// R15 emit: one thread per FOUR edges of the same row (k0 4-aligned).
// Every store is dwordx4 (src/dst/w: 16B/lane contiguous; vec: 3x16B/lane
// contiguous) -> zero partial-line write amplification, 1/4 the store
// instructions of R12. Keys load as one 8B read; 4 independent coord
// gathers per thread give ILP.
__global__ __launch_bounds__(256) void emit_edges(const float4* __restrict__ sortedg,
                                                  const u16* __restrict__ origg,
                                                  const u16* __restrict__ invpos,
                                                  const u16* __restrict__ keys,
                                                  float* __restrict__ out)
{
  const int t  = blockIdx.x * 256 + threadIdx.x;
  const int e0 = t * 4;                            // first of 4 edges
  const int r  = e0 >> 5;                          // orig row (= dst id)
  const int k0 = e0 & 31;                          // 0,4,...,28
  const int mb = r >> 10;
  const int molbase  = mb << 10;
  const int molbaseS = mb * SSTRIDE;
  const int spos = invpos[r];                      // broadcast within row

  const uint2 kw = *(const uint2*)(keys + (((size_t)(molbase + spos)) << 5) + k0);
  const u32 kk[4] = { kw.x & 0xFFFFu, kw.x >> 16, kw.y & 0xFFFFu, kw.y >> 16 };

  const float4 mc = sortedg[molbaseS + spos];      // broadcast within row
  float sv[4], wv[4], vv[12];
#pragma unroll
  for (int u = 0; u < 4; ++u) {
    const int idx = (int)(kk[u] & 1023u);
    const bool valid = (kk[u] & 1024u) != 0;
    const float4 cj = sortedg[molbaseS + idx];     // 16B gather, L1/L2-warm
    const float vx = (-0.5f*cj.x) - (-0.5f*mc.x);  // exact recovery
    const float vy = (-0.5f*cj.y) - (-0.5f*mc.y);
    const float vz = (-0.5f*cj.z) - (-0.5f*mc.z);
    const bool wm = valid && (idx != spos);
    wv[u] = wm ? sqrtf(vx*vx + vy*vy + vz*vz) : 0.0f;
    sv[u] = (float)molbase + (float)origg[molbase + idx];
    vv[3*u+0] = vx; vv[3*u+1] = vy; vv[3*u+2] = vz;
  }

  const long long E = (long long)NB * NM * NK;
  const float fr = (float)r;
  *(vf4*)(out + e0)       = (vf4){sv[0], sv[1], sv[2], sv[3]};   // src
  *(vf4*)(out + E + e0)   = (vf4){fr, fr, fr, fr};               // dst
  *(vf4*)(out + 2*E + e0) = (vf4){wv[0], wv[1], wv[2], wv[3]};   // weight
  vf4* pv = (vf4*)(out + 3*E + (size_t)e0 * 3);                  // vec
  pv[0] = (vf4){vv[0], vv[1], vv[2],  vv[3]};
  pv[1] = (vf4){vv[4], vv[5], vv[6],  vv[7]};
  pv[2] = (vf4){vv[8], vv[9], vv[10], vv[11]};
}

extern "C" void kernel_launch(void* const* d_in, const int* in_sizes, int n_in,
                              void* d_out, int out_size, void* d_ws, size_t ws_size,
                              hipStream_t stream) {
  const float* pos = (const float*)d_in[0];
  float* out = (float*)d_out;
  float4* sortedg = (float4*)d_ws;
  u16* origid  = (u16*)((char*)d_ws + OFF_ORIG);
  u16* startsg = (u16*)((char*)d_ws + OFF_STARTS);
  u16* invpos  = (u16*)((char*)d_ws + OFF_INV);
  u16* keys    = (u16*)((char*)d_ws + OFF_KEYS);

  hipLaunchKernelGGL(pack_bin, dim3(NB), dim3(256), 0, stream,
                     pos, sortedg, origid, invpos, startsg);
  if (ws_size >= WS_NEEDED) {
    hipLaunchKernelGGL((radius_knn<true>), dim3(NB * (NM / 64)), dim3(256), 0, stream,
                       sortedg, origid, startsg, keys, out);
    hipLaunchKernelGGL(emit_edges, dim3((int)(((long long)NB * NM * NK) / 1024)),
                       dim3(256), 0, stream, sortedg, origid, invpos, keys, out);
  } else {
    hipLaunchKernelGGL((radius_knn<false>), dim3(NB * (NM / 64)), dim3(256), 0, stream,
                       sortedg, origid, startsg, keys, out);
  }
}

// Round 11
// 161.076 us; speedup vs baseline: 1.0815x; 1.0815x over previous
//
#include <hip/hip_runtime.h>

#define NB 128
#define NM 1024
#define NK 32
#define NS 12                   // per-quarter survivor slots (avg ~7.6; P(>12)~3%)
#define CUT2 25.0f
#define CUT2_BITS 0x41C80000u   // bit pattern of 25.0f
#define KEYMASK   0xFFFFFC00u   // top 22 bits d2, low 10 bits index
#define INV_CELL  (1.0f/5.2f)   // 5x5x5 cells of 5.2 >= cutoff
#define NCELL3    125
#define SSTRIDE   1032          // sortedg row stride: 1024 atoms + 8 sentinels

// workspace layout (bytes)
#define OFF_ORIG   ((size_t)NB * SSTRIDE * 16)            // sortedg 2.11 MB
#define OFF_STARTS (OFF_ORIG + (size_t)(256u << 10))      // origid  256 KB
#define OFF_INV    (OFF_STARTS + (size_t)(32u << 10))     // startsg  32 KB
#define OFF_KEYS   (OFF_INV + (size_t)(256u << 10))       // invpos  256 KB
#define WS_NEEDED  (OFF_KEYS + (size_t)NB * NM * NK * 2)  // keys    8.39 MB

typedef unsigned int   u32;
typedef unsigned short u16;
typedef float vf4 __attribute__((ext_vector_type(4)));

// Prepass: bin atoms into 125 cells per molecule, write cell-sorted scan-form
// coords {-2x,-2y,-2z,|p|^2} + origid + invpos + cell-start table.
// 8 sentinel atoms (coords 1e15 -> d2 ~1e30) close each molecule's row: pad
// candidates (j=1024) fail the cutoff with no per-candidate test.
__global__ __launch_bounds__(256) void pack_bin(const float* __restrict__ pos,
                                                float4* __restrict__ sortedg,
                                                u16* __restrict__ origid,
                                                u16* __restrict__ invpos,
                                                u16* __restrict__ startsg)
{
  __shared__ u32 hist[NCELL3 + 1];
  __shared__ u32 starts[NCELL3 + 1];
  __shared__ u32 cur[NCELL3];
  const int tid = threadIdx.x;
  const int mb  = blockIdx.x;
  if (tid <= NCELL3) hist[tid] = 0;
  __syncthreads();

  float xx[4], yy[4], zz[4];
  int cid[4];
#pragma unroll
  for (int k = 0; k < 4; ++k) {
    int i  = k * 256 + tid;
    int gi = mb * NM + i;
    float x = pos[3*gi+0], y = pos[3*gi+1], z = pos[3*gi+2];
    xx[k] = x; yy[k] = y; zz[k] = z;
    int cx = (int)(x * INV_CELL); cx = cx > 4 ? 4 : cx;
    int cy = (int)(y * INV_CELL); cy = cy > 4 ? 4 : cy;
    int cz = (int)(z * INV_CELL); cz = cz > 4 ? 4 : cz;
    cid[k] = (cz * 5 + cy) * 5 + cx;
    atomicAdd(&hist[cid[k]], 1u);
  }
  __syncthreads();
  if (tid == 0) {
    u32 run = 0;
    for (int i = 0; i < NCELL3; ++i) { starts[i] = run; run += hist[i]; }
    starts[NCELL3] = run;                        // = 1024
  }
  __syncthreads();
  if (tid <= NCELL3) startsg[mb*(NCELL3+1) + tid] = (u16)starts[tid];
  if (tid <  NCELL3) cur[tid] = starts[tid];
  __syncthreads();
#pragma unroll
  for (int k = 0; k < 4; ++k) {
    int i = k * 256 + tid;
    u32 p = atomicAdd(&cur[cid[k]], 1u);
    float x = xx[k], y = yy[k], z = zz[k];
    sortedg[mb*SSTRIDE + p] = make_float4(-2.f*x, -2.f*y, -2.f*z, x*x + y*y + z*z);
    origid[mb*NM + p]  = (u16)i;
    invpos[mb*NM + i]  = (u16)p;
  }
  if (tid < 8)                                    // sentinels
    sortedg[mb*SSTRIDE + 1024 + tid] = make_float4(-2e15f, -2e15f, -2e15f, 1e30f);
}

__device__ __forceinline__ void ce_asc(u32 &a, u32 &b) {
  u32 mn = a < b ? a : b;
  u32 mx = a < b ? b : a;
  a = mn; b = mx;
}

template <int N, int K, int D>
__device__ __forceinline__ void bitonic_pass(u32* r) {
#pragma unroll
  for (int i = 0; i < N; ++i)
    if ((i & D) == 0) {
      if ((i & K) == 0) ce_asc(r[i], r[i | D]);
      else              ce_asc(r[i | D], r[i]);
    }
}

// R16: coords staged in LDS. R14/R15 scan loads were L2-latency-bound: a CU's
// ~8 resident blocks hold ~8 DIFFERENT molecules (130KB >> 32KB L1), so every
// broadcast load paid ~200cy; Little's law says ~25 outstanding/SIMD needed vs
// ~marginal available -> VALUBusy stuck ~45%, select 4x its VALU floor.
// Staging the molecule (16.5KB) makes scan loads wave-uniform ds_read_b128
// broadcasts (~10cy). LDS 33KB -> 4 blocks/CU (16 waves) — acceptable because
// the latency being hidden dropped 20x. Scan = R14 row-direct 2-wide; emit =
// R12 thread-per-edge (best measured); rest identical to passing R14.
template <bool SPLIT>
__global__ __launch_bounds__(256, 4) void radius_knn(const float4* __restrict__ sortedg,
                                                     const u16* __restrict__ origg,
                                                     const u16* __restrict__ startsg,
                                                     u16* __restrict__ keys,
                                                     float* __restrict__ out)
{
  __shared__ float4 s4[SSTRIDE];  // 16.5KB molecule coords (scan-form + sentinels)
  __shared__ u32 lmem[4096];      // 16KB: lists (12KB), later publish buf (16KB)
  __shared__ u16 st_s[128];       // 256B cell-start table
  __shared__ u16 orig_s[NM];      // 2KB sorted-pos -> orig (mono instantiation only)
  u32* lists = lmem;              // [NS][256] u32 = 12KB

  const int tid     = threadIdx.x;
  const int ctr     = tid & 63;
  const int quarter = tid >> 6;          // wave index
  const int molb    = blockIdx.x & 127;
  const int grp     = blockIdx.x >> 7;
  const int spos    = grp * 64 + ctr;    // center = sorted position
  const int molbase  = molb * NM;        // origg/keys stride
  const int molbaseS = molb * SSTRIDE;   // sortedg stride (with sentinels)

  for (int t = tid; t < SSTRIDE; t += 256) s4[t] = sortedg[molbaseS + t];
  if constexpr (!SPLIT)
    for (int t = tid; t < NM; t += 256) orig_s[t] = origg[molbase + t];
  if (tid <= NCELL3) st_s[tid] = startsg[molb*(NCELL3+1) + tid];

  const float4 mc  = sortedg[molbaseS + spos];   // global (pre-barrier), coalesced
  const float mex = -0.5f*mc.x, mey = -0.5f*mc.y, mez = -0.5f*mc.z;
  const float mew = mc.w;

  // block cell bounds (every wave reduces over the same 64 centers)
  int cx = (int)(mex * INV_CELL); cx = cx > 4 ? 4 : cx;
  int cy = (int)(mey * INV_CELL); cy = cy > 4 ? 4 : cy;
  int cz = (int)(mez * INV_CELL); cz = cz > 4 ? 4 : cz;
  int mnx = cx, mxx = cx, mny = cy, mxy = cy, mnz = cz, mxz = cz;
#pragma unroll
  for (int m = 32; m; m >>= 1) {
    mnx = min(mnx, __shfl_xor(mnx, m, 64)); mxx = max(mxx, __shfl_xor(mxx, m, 64));
    mny = min(mny, __shfl_xor(mny, m, 64)); mxy = max(mxy, __shfl_xor(mxy, m, 64));
    mnz = min(mnz, __shfl_xor(mnz, m, 64)); mxz = max(mxz, __shfl_xor(mxz, m, 64));
  }
  __syncthreads();                                   // s4, st_s (and orig_s) ready

  const int zlo = max(mnz-1, 0), zhi = min(mxz+1, 4);
  const int ylo = max(mny-1, 0), yhi = min(mxy+1, 4);
  const int xlo = max(mnx-1, 0), xhi = min(mxx+1, 4);

  // ---- phase 1: scan dilated-bbox rows, quarter-interleaved mod 4,
  //      coords from LDS (wave-uniform ds_read_b128 broadcast) ----
  int cnt = 0;
#define PROC(cj, jv)                                                        \
    {                                                                       \
      float d2 = fmaxf(__builtin_fmaf(mex, cj.x, __builtin_fmaf(mey, cj.y, \
                 __builtin_fmaf(mez, cj.z, mew + cj.w))), 0.f);             \
      u32 key = (__float_as_uint(d2) & KEYMASK) | (u32)((jv) & 1023u);      \
      int slot = cnt < NS ? cnt : (NS - 1);                                 \
      lists[slot * 256 + tid] = key;                                        \
      cnt += (d2 <= CUT2) ? 1 : 0;                                          \
    }
  for (int rz = zlo; rz <= zhi; ++rz)
    for (int ry = ylo; ry <= yhi; ++ry) {
      const int rowb = (rz*5 + ry)*5;
      const int rs = st_s[rowb + xlo];
      const int re = st_s[rowb + xhi + 1];
      for (int j = rs + quarter; j < re; j += 8) {
        int jb = j + 4;
        int j2 = jb < re ? jb : 1024;              // sentinel: fails cutoff
        float4 ca = s4[j];
        float4 cb = s4[j2];
        PROC(ca, j)
        PROC(cb, j2)
      }
    }
#undef PROC
  if (cnt > NS) cnt = NS;

  // ---- phase 2: keys straight from LDS + bitonic sort 16 ----
  const u32 PADK = 0x7F800000u | (u32)spos;   // +inf self-pad, sorts last
  u32 r[32];
#pragma unroll
  for (int k = 0; k < 16; ++k)
    r[k] = (k < cnt) ? lists[k * 256 + tid] : PADK;
  bitonic_pass<16, 2, 1>(r);
  bitonic_pass<16, 4, 2>(r); bitonic_pass<16, 4, 1>(r);
  bitonic_pass<16, 8, 4>(r); bitonic_pass<16, 8, 2>(r); bitonic_pass<16, 8, 1>(r);
  bitonic_pass<16,16, 8>(r); bitonic_pass<16,16, 4>(r); bitonic_pass<16,16, 2>(r); bitonic_pass<16,16, 1>(r);

  // ---- phase 3a: symmetric pair merge (q0<->q1, q2<->q3), 16 keys ----
  __syncthreads();                       // lists dead; lmem = publish buf
  {
    u32* myp = lmem + quarter * 1024 + ctr * 16;
#pragma unroll
    for (int k = 0; k < 16; ++k) myp[(k + ctr) & 15] = r[k];   // bank-swizzled
  }
  __syncthreads();
  if (!SPLIT || (quarter & 1) == 0) {    // SPLIT: only publishers need pair-32
    u32* op = lmem + (quarter ^ 1) * 1024 + ctr * 16;
#pragma unroll
    for (int i = 0; i < 16; ++i) r[16 + i] = op[((15 - i) + ctr) & 15]; // desc
    bitonic_pass<32,32,16>(r); bitonic_pass<32,32, 8>(r); bitonic_pass<32,32, 4>(r);
    bitonic_pass<32,32, 2>(r); bitonic_pass<32,32, 1>(r);
  }

  // ---- phase 3b: cross-pair merge ----
  __syncthreads();
  const int pairId = quarter >> 1;
  if ((quarter & 1) == 0) {
    u32* pp = lmem + pairId * 2048 + ctr * 32;
#pragma unroll
    for (int k = 0; k < 32; ++k) pp[(k + ctr) & 31] = r[k];
  }
  __syncthreads();
  if (!SPLIT || quarter == 0) {          // SPLIT: only q0 needs the final 32
    u32* opp = lmem + (1 - pairId) * 2048 + ctr * 32;
#pragma unroll
    for (int t = 0; t < 32; ++t) {
      u32 v = opp[((31 - t) + ctr) & 31];            // other pair, descending
      r[t] = r[t] < v ? r[t] : v;                    // lower half of bitonic-64
    }
    bitonic_pass<32,32,16>(r); bitonic_pass<32,32, 8>(r); bitonic_pass<32,32, 4>(r);
    bitonic_pass<32,32, 2>(r); bitonic_pass<32,32, 1>(r);
  }

  if constexpr (SPLIT) {
    // ---- phase 4 (split): q0 stores packed u16 keys, coalesced by spos ----
    if (quarter == 0) {
      u32 pk[16];
#pragma unroll
      for (int i = 0; i < 16; ++i) {
        u32 klo = r[2*i], khi = r[2*i+1];
        u32 plo = (((klo & KEYMASK) <= CUT2_BITS) ? 1024u : 0u) | (klo & 1023u);
        u32 phi = (((khi & KEYMASK) <= CUT2_BITS) ? 1024u : 0u) | (khi & 1023u);
        pk[i] = plo | (phi << 16);
      }
      uint4* kp = (uint4*)(keys + (size_t)(molbase + spos) * 32);
#pragma unroll
      for (int i = 0; i < 4; ++i)
        kp[i] = make_uint4(pk[4*i], pk[4*i+1], pk[4*i+2], pk[4*i+3]);
    }
    return;
  } else {
    // ---- phase 4 (mono fallback): scattered emit, one role per wave ----
    const int mloc = orig_s[spos];
    const int c = molbase + mloc;
    const long long E = (long long)NB * NM * NK;
    const float base = (float)molbase;
    const float nmex = -mex, nmey = -mey, nmez = -mez;

    if (quarter == 0) {                    // src + dst
      vf4* ps = (vf4*)(out       + (size_t)c * NK);
      vf4* pd = (vf4*)(out +   E + (size_t)c * NK);
      const float fc = (float)c;
      const vf4 dstv = {fc, fc, fc, fc};
#pragma unroll
      for (int q = 0; q < 8; ++q) {
        float sv[4];
#pragma unroll
        for (int u = 0; u < 4; ++u) {
          int idx = (int)(r[4*q + u] & 1023u);
          sv[u] = base + (float)orig_s[idx];
        }
        ps[q] = (vf4){sv[0], sv[1], sv[2], sv[3]};
        pd[q] = dstv;
      }
    } else if (quarter == 1) {             // weights
      vf4* pw = (vf4*)(out + 2*E + (size_t)c * NK);
#pragma unroll
      for (int q = 0; q < 8; ++q) {
        float wv[4];
#pragma unroll
        for (int u = 0; u < 4; ++u) {
          u32 key = r[4*q + u];
          int idx = (int)(key & 1023u);
          float4 cj = s4[idx];
          bool valid = (key & KEYMASK) <= CUT2_BITS;
          float vx = __builtin_fmaf(-0.5f, cj.x, nmex);
          float vy = __builtin_fmaf(-0.5f, cj.y, nmey);
          float vz = __builtin_fmaf(-0.5f, cj.z, nmez);
          bool wm  = valid && (idx != spos);
          float d2s = vx*vx + vy*vy + vz*vz;
          wv[u] = wm ? sqrtf(d2s) : 0.0f;
        }
        pw[q] = (vf4){wv[0], wv[1], wv[2], wv[3]};
      }
    } else if (quarter == 2) {             // edge vectors 0..15
      vf4* pv = (vf4*)(out + 3*E + (size_t)c * NK * 3);
#pragma unroll
      for (int q = 0; q < 4; ++q) {
        float vv[12];
#pragma unroll
        for (int u = 0; u < 4; ++u) {
          int idx = (int)(r[4*q + u] & 1023u);
          float4 cj = s4[idx];
          vv[3*u+0] = __builtin_fmaf(-0.5f, cj.x, nmex);
          vv[3*u+1] = __builtin_fmaf(-0.5f, cj.y, nmey);
          vv[3*u+2] = __builtin_fmaf(-0.5f, cj.z, nmez);
        }
        pv[3*q+0] = (vf4){vv[0], vv[1], vv[2],  vv[3]};
        pv[3*q+1] = (vf4){vv[4], vv[5], vv[6],  vv[7]};
        pv[3*q+2] = (vf4){vv[8], vv[9], vv[10], vv[11]};
      }
    } else {                               // edge vectors 16..31
      vf4* pv = (vf4*)(out + 3*E + (size_t)c * NK * 3) + 12;
#pragma unroll
      for (int q = 0; q < 4; ++q) {
        float vv[12];
#pragma unroll
        for (int u = 0; u < 4; ++u) {
          int idx = (int)(r[16 + 4*q + u] & 1023u);
          float4 cj = s4[idx];
          vv[3*u+0] = __builtin_fmaf(-0.5f, cj.x, nmex);
          vv[3*u+1] = __builtin_fmaf(-0.5f, cj.y, nmey);
          vv[3*u+2] = __builtin_fmaf(-0.5f, cj.z, nmez);
        }
        pv[3*q+0] = (vf4){vv[0], vv[1], vv[2],  vv[3]};
        pv[3*q+1] = (vf4){vv[4], vv[5], vv[6],  vv[7]};
        pv[3*q+2] = (vf4){vv[8], vv[9], vv[10], vv[11]};
      }
    }
  }
}

// Emit (R12, best measured): one thread per EDGE. All stores instruction-
// coalesced: src/dst/w are 4B/lane contiguous, vec is 12B/lane contiguous.
// Loads: invpos+keys coalesced/broadcast, one 16B coord gather (L1/L2-warm).
__global__ __launch_bounds__(256) void emit_edges(const float4* __restrict__ sortedg,
                                                  const u16* __restrict__ origg,
                                                  const u16* __restrict__ invpos,
                                                  const u16* __restrict__ keys,
                                                  float* __restrict__ out)
{
  const int e = blockIdx.x * 256 + threadIdx.x;    // edge id
  const int r = e >> 5;                            // orig row (= dst id)
  const int k = e & 31;
  const int mb = r >> 10;
  const int molbase  = mb << 10;
  const int molbaseS = mb * SSTRIDE;
  const int spos = invpos[r];                      // broadcast within row

  const u16 key = keys[((size_t)(molbase + spos) << 5) + k];  // coalesced
  const int idx = (int)(key & 1023u);
  const bool valid = (key & 1024u) != 0;

  const float4 mc = sortedg[molbaseS + spos];      // broadcast within row
  const float4 cj = sortedg[molbaseS + idx];       // 16B gather, L1/L2-warm
  const float vx = (-0.5f*cj.x) - (-0.5f*mc.x);    // exact recovery, 1 rounding
  const float vy = (-0.5f*cj.y) - (-0.5f*mc.y);
  const float vz = (-0.5f*cj.z) - (-0.5f*mc.z);
  const bool wm = valid && (idx != spos);
  const float w = wm ? sqrtf(vx*vx + vy*vy + vz*vz) : 0.0f;

  const long long E = (long long)NB * NM * NK;
  out[e]       = (float)molbase + (float)origg[molbase + idx];  // src
  out[E + e]   = (float)r;                                      // dst
  out[2*E + e] = w;                                             // weight
  float* pv = out + 3*E + (size_t)e * 3;                        // vec
  pv[0] = vx; pv[1] = vy; pv[2] = vz;
}

extern "C" void kernel_launch(void* const* d_in, const int* in_sizes, int n_in,
                              void* d_out, int out_size, void* d_ws, size_t ws_size,
                              hipStream_t stream) {
  const float* pos = (const float*)d_in[0];
  float* out = (float*)d_out;
  float4* sortedg = (float4*)d_ws;
  u16* origid  = (u16*)((char*)d_ws + OFF_ORIG);
  u16* startsg = (u16*)((char*)d_ws + OFF_STARTS);
  u16* invpos  = (u16*)((char*)d_ws + OFF_INV);
  u16* keys    = (u16*)((char*)d_ws + OFF_KEYS);

  hipLaunchKernelGGL(pack_bin, dim3(NB), dim3(256), 0, stream,
                     pos, sortedg, origid, invpos, startsg);
  if (ws_size >= WS_NEEDED) {
    hipLaunchKernelGGL((radius_knn<true>), dim3(NB * (NM / 64)), dim3(256), 0, stream,
                       sortedg, origid, startsg, keys, out);
    hipLaunchKernelGGL(emit_edges, dim3((int)(((long long)NB * NM * NK) / 256)),
                       dim3(256), 0, stream, sortedg, origid, invpos, keys, out);
  } else {
    hipLaunchKernelGGL((radius_knn<false>), dim3(NB * (NM / 64)), dim3(256), 0, stream,
                       sortedg, origid, startsg, keys, out);
  }
}

// Round 12
// 160.250 us; speedup vs baseline: 1.0871x; 1.0052x over previous
//
#include <hip/hip_runtime.h>

#define NB 128
#define NM 1024
#define NK 32
#define NS 12                   // per-quarter survivor slots (avg ~7.6; P(>12)~3%)
#define CUT2 25.0f
#define CUT2_BITS 0x41C80000u   // bit pattern of 25.0f
#define KEYMASK   0xFFFFFC00u   // top 22 bits d2, low 10 bits index
#define INV_CELL  (1.0f/5.2f)   // 5x5x5 cells of 5.2 >= cutoff
#define NCELL3    125
#define SSTRIDE   1032          // sortedg row stride: 1024 atoms + 8 sentinels
#define SLDS      1025          // LDS copy: 1024 atoms + 1 sentinel (idx 1024)

// workspace layout (bytes)
#define OFF_ORIG   ((size_t)NB * SSTRIDE * 16)            // sortedg 2.11 MB
#define OFF_STARTS (OFF_ORIG + (size_t)(256u << 10))      // origid  256 KB
#define OFF_INV    (OFF_STARTS + (size_t)(32u << 10))     // startsg  32 KB
#define OFF_KEYS   (OFF_INV + (size_t)(256u << 10))       // invpos  256 KB
#define WS_NEEDED  (OFF_KEYS + (size_t)NB * NM * NK * 2)  // keys    8.39 MB

typedef unsigned int   u32;
typedef unsigned short u16;
typedef float vf4 __attribute__((ext_vector_type(4)));

// Prepass: bin atoms into 125 cells per molecule, write cell-sorted scan-form
// coords {-2x,-2y,-2z,|p|^2} + origid + invpos + cell-start table.
// Sentinel atoms (coords 1e15 -> d2 ~1e30) close each molecule's row: pad
// candidates (j=1024) fail the cutoff with no per-candidate test.
__global__ __launch_bounds__(256) void pack_bin(const float* __restrict__ pos,
                                                float4* __restrict__ sortedg,
                                                u16* __restrict__ origid,
                                                u16* __restrict__ invpos,
                                                u16* __restrict__ startsg)
{
  __shared__ u32 hist[NCELL3 + 1];
  __shared__ u32 starts[NCELL3 + 1];
  __shared__ u32 cur[NCELL3];
  const int tid = threadIdx.x;
  const int mb  = blockIdx.x;
  if (tid <= NCELL3) hist[tid] = 0;
  __syncthreads();

  float xx[4], yy[4], zz[4];
  int cid[4];
#pragma unroll
  for (int k = 0; k < 4; ++k) {
    int i  = k * 256 + tid;
    int gi = mb * NM + i;
    float x = pos[3*gi+0], y = pos[3*gi+1], z = pos[3*gi+2];
    xx[k] = x; yy[k] = y; zz[k] = z;
    int cx = (int)(x * INV_CELL); cx = cx > 4 ? 4 : cx;
    int cy = (int)(y * INV_CELL); cy = cy > 4 ? 4 : cy;
    int cz = (int)(z * INV_CELL); cz = cz > 4 ? 4 : cz;
    cid[k] = (cz * 5 + cy) * 5 + cx;
    atomicAdd(&hist[cid[k]], 1u);
  }
  __syncthreads();
  if (tid == 0) {
    u32 run = 0;
    for (int i = 0; i < NCELL3; ++i) { starts[i] = run; run += hist[i]; }
    starts[NCELL3] = run;                        // = 1024
  }
  __syncthreads();
  if (tid <= NCELL3) startsg[mb*(NCELL3+1) + tid] = (u16)starts[tid];
  if (tid <  NCELL3) cur[tid] = starts[tid];
  __syncthreads();
#pragma unroll
  for (int k = 0; k < 4; ++k) {
    int i = k * 256 + tid;
    u32 p = atomicAdd(&cur[cid[k]], 1u);
    float x = xx[k], y = yy[k], z = zz[k];
    sortedg[mb*SSTRIDE + p] = make_float4(-2.f*x, -2.f*y, -2.f*z, x*x + y*y + z*z);
    origid[mb*NM + p]  = (u16)i;
    invpos[mb*NM + i]  = (u16)p;
  }
  if (tid < 8)                                    // sentinels
    sortedg[mb*SSTRIDE + 1024 + tid] = make_float4(-2e15f, -2e15f, -2e15f, 1e30f);
}

__device__ __forceinline__ void ce_asc(u32 &a, u32 &b) {
  u32 mn = a < b ? a : b;
  u32 mx = a < b ? b : a;
  a = mn; b = mx;
}

template <int N, int K, int D>
__device__ __forceinline__ void bitonic_pass(u32* r) {
#pragma unroll
  for (int i = 0; i < N; ++i)
    if ((i & D) == 0) {
      if ((i & K) == 0) ce_asc(r[i], r[i | D]);
      else              ce_asc(r[i | D], r[i]);
    }
}

// R17: LDS diet for occupancy. R16's staging fixed the L2-latency stall but
// cost occupancy (35KB -> 4 blocks/CU, 16 waves). In the SPLIT path s4 is
// DEAD after phase 1 (phase 2 reads keys from lists; phase 4 reads registers)
// -> the 16KB publish buffer aliases s4, lmem shrinks to the 12KB lists, and
// orig_s is mono-only. SPLIT footprint 35 -> 28.9KB -> 5 blocks/CU, 20 waves
// (+25%). Everything else byte-identical to R16 (passed, 161us).
template <bool SPLIT>
__global__ __launch_bounds__(256, 5) void radius_knn(const float4* __restrict__ sortedg,
                                                     const u16* __restrict__ origg,
                                                     const u16* __restrict__ startsg,
                                                     u16* __restrict__ keys,
                                                     float* __restrict__ out)
{
  __shared__ float4 s4[SLDS];     // 16.4KB coords; SPLIT: publish buf after ph1
  __shared__ u32 lists[NS * 256]; // 12KB survivor lists
  __shared__ u16 st_s[128];       // 256B cell-start table
  __shared__ u16 orig_s[SPLIT ? 1 : NM];     // mono-only (2KB)
  __shared__ u32 pub_mono[SPLIT ? 1 : 4096]; // mono-only publish (16KB)
  u32* pub;
  if constexpr (SPLIT) pub = (u32*)s4;       // s4 dead after phase 1
  else                 pub = pub_mono;       // s4 needed in phase 4

  const int tid     = threadIdx.x;
  const int ctr     = tid & 63;
  const int quarter = tid >> 6;          // wave index
  const int molb    = blockIdx.x & 127;
  const int grp     = blockIdx.x >> 7;
  const int spos    = grp * 64 + ctr;    // center = sorted position
  const int molbase  = molb * NM;        // origg/keys stride
  const int molbaseS = molb * SSTRIDE;   // sortedg stride (with sentinels)

  for (int t = tid; t < SLDS; t += 256) s4[t] = sortedg[molbaseS + t];
  if constexpr (!SPLIT)
    for (int t = tid; t < NM; t += 256) orig_s[t] = origg[molbase + t];
  if (tid <= NCELL3) st_s[tid] = startsg[molb*(NCELL3+1) + tid];

  const float4 mc  = sortedg[molbaseS + spos];   // global (pre-barrier), coalesced
  const float mex = -0.5f*mc.x, mey = -0.5f*mc.y, mez = -0.5f*mc.z;
  const float mew = mc.w;

  // block cell bounds (every wave reduces over the same 64 centers)
  int cx = (int)(mex * INV_CELL); cx = cx > 4 ? 4 : cx;
  int cy = (int)(mey * INV_CELL); cy = cy > 4 ? 4 : cy;
  int cz = (int)(mez * INV_CELL); cz = cz > 4 ? 4 : cz;
  int mnx = cx, mxx = cx, mny = cy, mxy = cy, mnz = cz, mxz = cz;
#pragma unroll
  for (int m = 32; m; m >>= 1) {
    mnx = min(mnx, __shfl_xor(mnx, m, 64)); mxx = max(mxx, __shfl_xor(mxx, m, 64));
    mny = min(mny, __shfl_xor(mny, m, 64)); mxy = max(mxy, __shfl_xor(mxy, m, 64));
    mnz = min(mnz, __shfl_xor(mnz, m, 64)); mxz = max(mxz, __shfl_xor(mxz, m, 64));
  }
  __syncthreads();                                   // s4, st_s (and orig_s) ready

  const int zlo = max(mnz-1, 0), zhi = min(mxz+1, 4);
  const int ylo = max(mny-1, 0), yhi = min(mxy+1, 4);
  const int xlo = max(mnx-1, 0), xhi = min(mxx+1, 4);

  // ---- phase 1: scan dilated-bbox rows, quarter-interleaved mod 4,
  //      coords from LDS (wave-uniform ds_read_b128 broadcast) ----
  int cnt = 0;
#define PROC(cj, jv)                                                        \
    {                                                                       \
      float d2 = fmaxf(__builtin_fmaf(mex, cj.x, __builtin_fmaf(mey, cj.y, \
                 __builtin_fmaf(mez, cj.z, mew + cj.w))), 0.f);             \
      u32 key = (__float_as_uint(d2) & KEYMASK) | (u32)((jv) & 1023u);      \
      int slot = cnt < NS ? cnt : (NS - 1);                                 \
      lists[slot * 256 + tid] = key;                                        \
      cnt += (d2 <= CUT2) ? 1 : 0;                                          \
    }
  for (int rz = zlo; rz <= zhi; ++rz)
    for (int ry = ylo; ry <= yhi; ++ry) {
      const int rowb = (rz*5 + ry)*5;
      const int rs = st_s[rowb + xlo];
      const int re = st_s[rowb + xhi + 1];
      for (int j = rs + quarter; j < re; j += 8) {
        int jb = j + 4;
        int j2 = jb < re ? jb : 1024;              // sentinel: fails cutoff
        float4 ca = s4[j];
        float4 cb = s4[j2];
        PROC(ca, j)
        PROC(cb, j2)
      }
    }
#undef PROC
  if (cnt > NS) cnt = NS;

  // ---- phase 2: keys straight from LDS + bitonic sort 16 ----
  const u32 PADK = 0x7F800000u | (u32)spos;   // +inf self-pad, sorts last
  u32 r[32];
#pragma unroll
  for (int k = 0; k < 16; ++k)
    r[k] = (k < cnt) ? lists[k * 256 + tid] : PADK;
  bitonic_pass<16, 2, 1>(r);
  bitonic_pass<16, 4, 2>(r); bitonic_pass<16, 4, 1>(r);
  bitonic_pass<16, 8, 4>(r); bitonic_pass<16, 8, 2>(r); bitonic_pass<16, 8, 1>(r);
  bitonic_pass<16,16, 8>(r); bitonic_pass<16,16, 4>(r); bitonic_pass<16,16, 2>(r); bitonic_pass<16,16, 1>(r);

  // ---- phase 3a: symmetric pair merge (q0<->q1, q2<->q3), 16 keys ----
  __syncthreads();                       // all s4/list reads done; pub live
  {
    u32* myp = pub + quarter * 1024 + ctr * 16;
#pragma unroll
    for (int k = 0; k < 16; ++k) myp[(k + ctr) & 15] = r[k];   // bank-swizzled
  }
  __syncthreads();
  if (!SPLIT || (quarter & 1) == 0) {    // SPLIT: only publishers need pair-32
    u32* op = pub + (quarter ^ 1) * 1024 + ctr * 16;
#pragma unroll
    for (int i = 0; i < 16; ++i) r[16 + i] = op[((15 - i) + ctr) & 15]; // desc
    bitonic_pass<32,32,16>(r); bitonic_pass<32,32, 8>(r); bitonic_pass<32,32, 4>(r);
    bitonic_pass<32,32, 2>(r); bitonic_pass<32,32, 1>(r);
  }

  // ---- phase 3b: cross-pair merge ----
  __syncthreads();
  const int pairId = quarter >> 1;
  if ((quarter & 1) == 0) {
    u32* pp = pub + pairId * 2048 + ctr * 32;
#pragma unroll
    for (int k = 0; k < 32; ++k) pp[(k + ctr) & 31] = r[k];
  }
  __syncthreads();
  if (!SPLIT || quarter == 0) {          // SPLIT: only q0 needs the final 32
    u32* opp = pub + (1 - pairId) * 2048 + ctr * 32;
#pragma unroll
    for (int t = 0; t < 32; ++t) {
      u32 v = opp[((31 - t) + ctr) & 31];            // other pair, descending
      r[t] = r[t] < v ? r[t] : v;                    // lower half of bitonic-64
    }
    bitonic_pass<32,32,16>(r); bitonic_pass<32,32, 8>(r); bitonic_pass<32,32, 4>(r);
    bitonic_pass<32,32, 2>(r); bitonic_pass<32,32, 1>(r);
  }

  if constexpr (SPLIT) {
    // ---- phase 4 (split): q0 stores packed u16 keys, coalesced by spos ----
    if (quarter == 0) {
      u32 pk[16];
#pragma unroll
      for (int i = 0; i < 16; ++i) {
        u32 klo = r[2*i], khi = r[2*i+1];
        u32 plo = (((klo & KEYMASK) <= CUT2_BITS) ? 1024u : 0u) | (klo & 1023u);
        u32 phi = (((khi & KEYMASK) <= CUT2_BITS) ? 1024u : 0u) | (khi & 1023u);
        pk[i] = plo | (phi << 16);
      }
      uint4* kp = (uint4*)(keys + (size_t)(molbase + spos) * 32);
#pragma unroll
      for (int i = 0; i < 4; ++i)
        kp[i] = make_uint4(pk[4*i], pk[4*i+1], pk[4*i+2], pk[4*i+3]);
    }
    return;
  } else {
    // ---- phase 4 (mono fallback): scattered emit, one role per wave ----
    const int mloc = orig_s[spos];
    const int c = molbase + mloc;
    const long long E = (long long)NB * NM * NK;
    const float base = (float)molbase;
    const float nmex = -mex, nmey = -mey, nmez = -mez;

    if (quarter == 0) {                    // src + dst
      vf4* ps = (vf4*)(out       + (size_t)c * NK);
      vf4* pd = (vf4*)(out +   E + (size_t)c * NK);
      const float fc = (float)c;
      const vf4 dstv = {fc, fc, fc, fc};
#pragma unroll
      for (int q = 0; q < 8; ++q) {
        float sv[4];
#pragma unroll
        for (int u = 0; u < 4; ++u) {
          int idx = (int)(r[4*q + u] & 1023u);
          sv[u] = base + (float)orig_s[idx];
        }
        ps[q] = (vf4){sv[0], sv[1], sv[2], sv[3]};
        pd[q] = dstv;
      }
    } else if (quarter == 1) {             // weights
      vf4* pw = (vf4*)(out + 2*E + (size_t)c * NK);
#pragma unroll
      for (int q = 0; q < 8; ++q) {
        float wv[4];
#pragma unroll
        for (int u = 0; u < 4; ++u) {
          u32 key = r[4*q + u];
          int idx = (int)(key & 1023u);
          float4 cj = s4[idx];
          bool valid = (key & KEYMASK) <= CUT2_BITS;
          float vx = __builtin_fmaf(-0.5f, cj.x, nmex);
          float vy = __builtin_fmaf(-0.5f, cj.y, nmey);
          float vz = __builtin_fmaf(-0.5f, cj.z, nmez);
          bool wm  = valid && (idx != spos);
          float d2s = vx*vx + vy*vy + vz*vz;
          wv[u] = wm ? sqrtf(d2s) : 0.0f;
        }
        pw[q] = (vf4){wv[0], wv[1], wv[2], wv[3]};
      }
    } else if (quarter == 2) {             // edge vectors 0..15
      vf4* pv = (vf4*)(out + 3*E + (size_t)c * NK * 3);
#pragma unroll
      for (int q = 0; q < 4; ++q) {
        float vv[12];
#pragma unroll
        for (int u = 0; u < 4; ++u) {
          int idx = (int)(r[4*q + u] & 1023u);
          float4 cj = s4[idx];
          vv[3*u+0] = __builtin_fmaf(-0.5f, cj.x, nmex);
          vv[3*u+1] = __builtin_fmaf(-0.5f, cj.y, nmey);
          vv[3*u+2] = __builtin_fmaf(-0.5f, cj.z, nmez);
        }
        pv[3*q+0] = (vf4){vv[0], vv[1], vv[2],  vv[3]};
        pv[3*q+1] = (vf4){vv[4], vv[5], vv[6],  vv[7]};
        pv[3*q+2] = (vf4){vv[8], vv[9], vv[10], vv[11]};
      }
    } else {                               // edge vectors 16..31
      vf4* pv = (vf4*)(out + 3*E + (size_t)c * NK * 3) + 12;
#pragma unroll
      for (int q = 0; q < 4; ++q) {
        float vv[12];
#pragma unroll
        for (int u = 0; u < 4; ++u) {
          int idx = (int)(r[16 + 4*q + u] & 1023u);
          float4 cj = s4[idx];
          vv[3*u+0] = __builtin_fmaf(-0.5f, cj.x, nmex);
          vv[3*u+1] = __builtin_fmaf(-0.5f, cj.y, nmey);
          vv[3*u+2] = __builtin_fmaf(-0.5f, cj.z, nmez);
        }
        pv[3*q+0] = (vf4){vv[0], vv[1], vv[2],  vv[3]};
        pv[3*q+1] = (vf4){vv[4], vv[5], vv[6],  vv[7]};
        pv[3*q+2] = (vf4){vv[8], vv[9], vv[10], vv[11]};
      }
    }
  }
}

// Emit (R12, best measured): one thread per EDGE. All stores instruction-
// coalesced: src/dst/w are 4B/lane contiguous, vec is 12B/lane contiguous.
// Loads: invpos+keys coalesced/broadcast, one 16B coord gather (L1/L2-warm).
__global__ __launch_bounds__(256) void emit_edges(const float4* __restrict__ sortedg,
                                                  const u16* __restrict__ origg,
                                                  const u16* __restrict__ invpos,
                                                  const u16* __restrict__ keys,
                                                  float* __restrict__ out)
{
  const int e = blockIdx.x * 256 + threadIdx.x;    // edge id
  const int r = e >> 5;                            // orig row (= dst id)
  const int k = e & 31;
  const int mb = r >> 10;
  const int molbase  = mb << 10;
  const int molbaseS = mb * SSTRIDE;
  const int spos = invpos[r];                      // broadcast within row

  const u16 key = keys[((size_t)(molbase + spos) << 5) + k];  // coalesced
  const int idx = (int)(key & 1023u);
  const bool valid = (key & 1024u) != 0;

  const float4 mc = sortedg[molbaseS + spos];      // broadcast within row
  const float4 cj = sortedg[molbaseS + idx];       // 16B gather, L1/L2-warm
  const float vx = (-0.5f*cj.x) - (-0.5f*mc.x);    // exact recovery, 1 rounding
  const float vy = (-0.5f*cj.y) - (-0.5f*mc.y);
  const float vz = (-0.5f*cj.z) - (-0.5f*mc.z);
  const bool wm = valid && (idx != spos);
  const float w = wm ? sqrtf(vx*vx + vy*vy + vz*vz) : 0.0f;

  const long long E = (long long)NB * NM * NK;
  out[e]       = (float)molbase + (float)origg[molbase + idx];  // src
  out[E + e]   = (float)r;                                      // dst
  out[2*E + e] = w;                                             // weight
  float* pv = out + 3*E + (size_t)e * 3;                        // vec
  pv[0] = vx; pv[1] = vy; pv[2] = vz;
}

extern "C" void kernel_launch(void* const* d_in, const int* in_sizes, int n_in,
                              void* d_out, int out_size, void* d_ws, size_t ws_size,
                              hipStream_t stream) {
  const float* pos = (const float*)d_in[0];
  float* out = (float*)d_out;
  float4* sortedg = (float4*)d_ws;
  u16* origid  = (u16*)((char*)d_ws + OFF_ORIG);
  u16* startsg = (u16*)((char*)d_ws + OFF_STARTS);
  u16* invpos  = (u16*)((char*)d_ws + OFF_INV);
  u16* keys    = (u16*)((char*)d_ws + OFF_KEYS);

  hipLaunchKernelGGL(pack_bin, dim3(NB), dim3(256), 0, stream,
                     pos, sortedg, origid, invpos, startsg);
  if (ws_size >= WS_NEEDED) {
    hipLaunchKernelGGL((radius_knn<true>), dim3(NB * (NM / 64)), dim3(256), 0, stream,
                       sortedg, origid, startsg, keys, out);
    hipLaunchKernelGGL(emit_edges, dim3((int)(((long long)NB * NM * NK) / 256)),
                       dim3(256), 0, stream, sortedg, origid, invpos, keys, out);
  } else {
    hipLaunchKernelGGL((radius_knn<false>), dim3(NB * (NM / 64)), dim3(256), 0, stream,
                       sortedg, origid, startsg, keys, out);
  }
}